// Round 4
// baseline (129.606 us; speedup 1.0000x reference)
//
#include <hip/hip_runtime.h>
#include <math.h>

// BlockSharedRounding: forward = E2M1 hard quantization of |x|+delta,
// delta = 0.5*tanh(delta_raw) shared per 32-elem block.
// Outputs concatenated: [abs_hard (f32) | ord (f32)].
//
// Monolithic streaming kernel (R4):
//  - 8 consecutive elems/thread/group -> exactly 1 DP tanh per group
//    (double tanh rounded to f32 == correctly-rounded f32 tanh; bin
//     boundaries are razor-thin so bit-exactness is mandatory; R1/R2
//     showed inline DP tanh is ~free under the memory roof)
//  - no pre-kernel => no serialized launch in the graph
//  - NONTEMPORAL stores (R3: -19%, avoids cache-allocation interference)
//  - two independent group-streams per iteration for load ILP

typedef float f32x4 __attribute__((ext_vector_type(4)));

__device__ __forceinline__ void quant4(f32x4 xv, float d, f32x4& val, f32x4& ordf)
{
    #pragma unroll
    for (int j = 0; j < 4; ++j) {
        float a = fabsf(xv[j]) + d;          // abs folds into src modifier
        int o = 0;                           // ord = #bounds strictly below a
        o += a > 0.25f;
        o += a > 0.75f;
        o += a > 1.25f;
        o += a > 1.75f;
        o += a > 2.5f;
        o += a > 3.5f;
        o += a > 5.0f;
        // VALUES*2 packed as nibbles: {0,1,2,3,4,6,8,12} -> 0xC8643210
        val[j]  = (float)((0xC8643210u >> (o << 2)) & 0xFu) * 0.5f;
        ordf[j] = (float)o;
    }
}

__global__ __launch_bounds__(256) void bsr_kernel(
    const f32x4* __restrict__ x,
    const float* __restrict__ draw,
    f32x4* __restrict__ out_val,
    f32x4* __restrict__ out_ord,
    long long nGroups)                       // n/8 groups of 8 consecutive elems
{
    const long long T = (long long)gridDim.x * blockDim.x;
    long long g = (long long)blockIdx.x * blockDim.x + threadIdx.x;

    for (; g + T < nGroups; g += 2 * T) {
        const long long g0 = g, g1 = g + T;
        // issue all 4 independent 16B loads + 2 draw loads up front
        f32x4 a0 = x[2 * g0];
        f32x4 a1 = x[2 * g0 + 1];
        f32x4 b0 = x[2 * g1];
        f32x4 b1 = x[2 * g1 + 1];
        float d0 = 0.5f * (float)tanh((double)draw[g0 >> 2]);
        float d1 = 0.5f * (float)tanh((double)draw[g1 >> 2]);

        f32x4 va0, oa0, va1, oa1, vb0, ob0, vb1, ob1;
        quant4(a0, d0, va0, oa0);
        quant4(a1, d0, va1, oa1);
        quant4(b0, d1, vb0, ob0);
        quant4(b1, d1, vb1, ob1);

        __builtin_nontemporal_store(va0, &out_val[2 * g0]);
        __builtin_nontemporal_store(va1, &out_val[2 * g0 + 1]);
        __builtin_nontemporal_store(oa0, &out_ord[2 * g0]);
        __builtin_nontemporal_store(oa1, &out_ord[2 * g0 + 1]);
        __builtin_nontemporal_store(vb0, &out_val[2 * g1]);
        __builtin_nontemporal_store(vb1, &out_val[2 * g1 + 1]);
        __builtin_nontemporal_store(ob0, &out_ord[2 * g1]);
        __builtin_nontemporal_store(ob1, &out_ord[2 * g1 + 1]);
    }
    if (g < nGroups) {
        f32x4 a0 = x[2 * g];
        f32x4 a1 = x[2 * g + 1];
        float d = 0.5f * (float)tanh((double)draw[g >> 2]);
        f32x4 v0, o0, v1, o1;
        quant4(a0, d, v0, o0);
        quant4(a1, d, v1, o1);
        __builtin_nontemporal_store(v0, &out_val[2 * g]);
        __builtin_nontemporal_store(v1, &out_val[2 * g + 1]);
        __builtin_nontemporal_store(o0, &out_ord[2 * g]);
        __builtin_nontemporal_store(o1, &out_ord[2 * g + 1]);
    }
}

extern "C" void kernel_launch(void* const* d_in, const int* in_sizes, int n_in,
                              void* d_out, int out_size, void* d_ws, size_t ws_size,
                              hipStream_t stream) {
    const float* x    = (const float*)d_in[0];   // x_scaled, n elements
    const float* draw = (const float*)d_in[1];   // delta_raw, n/32 elements
    float* out = (float*)d_out;                  // [abs_hard | ord]

    long long n = (long long)in_sizes[0];        // 33,554,432
    long long nGroups = n >> 3;                  // 4,194,304 groups of 8

    const int block = 256;
    int grid = 2048;                             // 8 blocks/CU -> 32 waves/CU
    bsr_kernel<<<grid, block, 0, stream>>>(
        reinterpret_cast<const f32x4*>(x), draw,
        reinterpret_cast<f32x4*>(out),
        reinterpret_cast<f32x4*>(out + n), nGroups);
}

// Round 5
// 70.282 us; speedup vs baseline: 1.8441x; 1.8441x over previous
//
#include <hip/hip_runtime.h>
#include <math.h>

// BlockSharedRounding: forward = E2M1 hard quantization of |x|+delta,
// delta = 0.5*tanh(delta_raw) shared per 32-elem block.
// Outputs concatenated: [abs_hard (f32) | ord (f32)].
//
// R5: monolithic, wave-granular tanh.
//  - Per iteration a wave covers 2 unit-stride streams x 64 float4 = 8+8
//    distinct 32-blocks. ONE exec-masked DP-tanh call (lanes 0..15), then
//    __shfl broadcast. 32768 wave-calls total, overlapped under the ~70us
//    memory phase (R1 proved 65536 wave-calls hide at a 93us floor).
//  - ANTI-SPILL (R4 post-mortem): nothing vector-valued is live across the
//    libm call; x loads are issued after it. R4's 129us came from caller-save
//    scratch spills of 4 live f32x4 around two calls/iter.
//  - double tanh rounded to f32 == correctly-rounded f32 tanh (bit-exact vs
//    numpy ref; bin boundaries are razor-thin). NT stores (R3: -19%).

typedef float f32x4 __attribute__((ext_vector_type(4)));

__device__ __forceinline__ void quant4(f32x4 xv, float d, f32x4& val, f32x4& ordf)
{
    #pragma unroll
    for (int j = 0; j < 4; ++j) {
        float a = fabsf(xv[j]) + d;          // abs folds into src modifier
        int o = 0;                           // ord = #bounds strictly below a
        o += a > 0.25f;
        o += a > 0.75f;
        o += a > 1.25f;
        o += a > 1.75f;
        o += a > 2.5f;
        o += a > 3.5f;
        o += a > 5.0f;
        // VALUES*2 packed as nibbles: {0,1,2,3,4,6,8,12} -> 0xC8643210
        val[j]  = (float)((0xC8643210u >> (o << 2)) & 0xFu) * 0.5f;
        ordf[j] = (float)o;
    }
}

__global__ __launch_bounds__(256) void bsr_kernel(
    const f32x4* __restrict__ x,
    const float* __restrict__ draw,
    f32x4* __restrict__ out_val,
    f32x4* __restrict__ out_ord,
    int nVec,                                // n/4 float4 elements
    int nb)                                  // n/32 blocks
{
    const int T = gridDim.x * blockDim.x;    // float4 stride per grid step
    const int lane = threadIdx.x & 63;
    int v = blockIdx.x * blockDim.x + threadIdx.x;

    for (; v + T < nVec; v += 2 * T) {
        const int W = v - lane;              // wave-uniform float4 base, %64==0
        // one masked call computes all 16 deltas this wave needs (8 per stream)
        float t = 0.0f;
        if (lane < 16) {
            int bidx = (lane < 8) ? ((W >> 3) + lane)
                                  : (((W + T) >> 3) + (lane - 8));
            bidx = bidx < nb ? bidx : nb - 1;    // safety clamp (exact grids never OOB)
            t = 0.5f * (float)tanh((double)draw[bidx]);
        }
        const float d0 = __shfl(t, lane >> 3, 64);
        const float d1 = __shfl(t, 8 + (lane >> 3), 64);

        // loads issued only after the call: nothing vector-valued lives across it
        f32x4 a = x[v];
        f32x4 b = x[v + T];
        f32x4 va, oa, vb, ob;
        quant4(a, d0, va, oa);
        quant4(b, d1, vb, ob);
        __builtin_nontemporal_store(va, &out_val[v]);
        __builtin_nontemporal_store(oa, &out_ord[v]);
        __builtin_nontemporal_store(vb, &out_val[v + T]);
        __builtin_nontemporal_store(ob, &out_ord[v + T]);
    }
    if (v < nVec) {                          // tail (unused for n=2^25, kept for safety)
        float d = 0.5f * (float)tanh((double)draw[v >> 3]);
        f32x4 a = x[v];
        f32x4 va, oa;
        quant4(a, d, va, oa);
        __builtin_nontemporal_store(va, &out_val[v]);
        __builtin_nontemporal_store(oa, &out_ord[v]);
    }
}

extern "C" void kernel_launch(void* const* d_in, const int* in_sizes, int n_in,
                              void* d_out, int out_size, void* d_ws, size_t ws_size,
                              hipStream_t stream) {
    const float* x    = (const float*)d_in[0];   // x_scaled, n elements
    const float* draw = (const float*)d_in[1];   // delta_raw, n/32 elements
    float* out = (float*)d_out;                  // [abs_hard | ord]

    long long n = (long long)in_sizes[0];        // 33,554,432
    int nb      = in_sizes[1];                   // 1,048,576
    int nVec    = (int)(n >> 2);                 // 8,388,608

    const int block = 256;
    int grid = 2048;                             // T=524288; nVec/T=16 -> 8 iters, no tail
    bsr_kernel<<<grid, block, 0, stream>>>(
        reinterpret_cast<const f32x4*>(x), draw,
        reinterpret_cast<f32x4*>(out),
        reinterpret_cast<f32x4*>(out + n), nVec, nb);
}